// Round 15
// baseline (517.185 us; speedup 1.0000x reference)
//
#include <hip/hip_runtime.h>
#include <math.h>

typedef __attribute__((ext_vector_type(8))) _Float16 half8;
typedef __attribute__((ext_vector_type(4))) float f32x4;
typedef __attribute__((ext_vector_type(4))) unsigned int u32x4;

namespace {
constexpr int NS = 32000, PAD = 200, NT = 201, TOUT = 192, NMEL = 128;
constexpr int PW_STRIDE = 236;                 // u16; 472B row stride -> conflict-free reads
constexpr int NT2 = 13;                        // radix basis: N=208 (202 live), K=224 (200 live)
constexpr int BAS2_ELEMS = 7 * NT2 * 64 * 8;   // 46592 u16
constexpr int WIN_ELEMS  = 448;                // win frags [par][ks][lg][j]
constexpr int FB_OFF     = BAS2_ELEMS + WIN_ELEMS;   // 47040
constexpr int FB_ELEMS   = 7 * 8 * 64 * 8;     // 28672
constexpr int OUT_ROW_U16 = TOUT * NMEL * 2;   // 49152 u16 per out row
constexpr int MEL_OFF_U16 = OUT_ROW_U16 - NT * NMEL;  // mel fp16 packed in row tail
}

// audio-LDS XOR swizzle (elem bits [4:3] ^= bits [8:7]); 8-elem chunks stay contiguous.
__device__ __forceinline__ int swz(int e) { return e ^ (((e >> 7) & 3) << 3); }
__device__ __forceinline__ unsigned short f2h(float f) {
  _Float16 h = (_Float16)f; return __builtin_bit_cast(unsigned short, h);
}
__device__ __forceinline__ float h2f(unsigned short u) {
  return (float)__builtin_bit_cast(_Float16, u);
}
__device__ __forceinline__ float dppswap(float v) {   // lane^1 within quads
  int iv = __builtin_bit_cast(int, v);
  return __builtin_bit_cast(float,
      __builtin_amdgcn_mov_dpp(iv, 0xB1, 0xF, 0xF, true));  // quad_perm [1,0,3,2]
}

// ws tables, fp16:
//  [0, BAS2): radix DFT basis frag[ks][nt][lane][j]: n=ks*32+(lane>>4)*8+j, col=nt*16+(lane&15)
//             col even -> cos(2*pi*bin*n/200), odd -> sin; bin=col/2; zero for n>=200 or col>=202
//  [BAS2, +448): window frags [par][ks][lg][j] = win[ks*64+lg*16+2j+par] (0 for idx>=400)
//  [FB_OFF, +FB): mel fb frag[ks][nt][lane][j] (unchanged layout)
__global__ void setup_tables(unsigned short* __restrict__ ws) {
  int idx = blockIdx.x * 256 + threadIdx.x;
  if (idx < BAS2_ELEMS) {
    int j = idx & 7, lane = (idx >> 3) & 63, rest = idx >> 9;
    int nt = rest % NT2, ks = rest / NT2;
    int n   = ks * 32 + ((lane >> 4) << 3) + j;
    int col = nt * 16 + (lane & 15);
    float v = 0.f;
    if (n < 200 && col < 202) {
      int bin = col >> 1;
      int mm  = (bin * n) % 200;
      float th = (float)mm * 0.03141592653589793f;     // 2*pi/200
      v = (col & 1) ? sinf(th) : cosf(th);
    }
    ws[idx] = f2h(v);
  } else if (idx < FB_OFF) {
    int i2 = idx - BAS2_ELEMS;                          // [par][ks][lg][j]
    int j = i2 & 7, lg = (i2 >> 3) & 3, t = i2 >> 5;
    int ks = t % 7, par = t / 7;
    int m = ks * 64 + lg * 16 + 2 * j + par;
    float v = 0.f;
    if (m < 400) v = 0.5f * (1.0f - cosf((float)m * 0.015707963267948967f));
    ws[idx] = f2h(v);
  } else if (idx < FB_OFF + FB_ELEMS) {
    int i2 = idx - FB_OFF;
    int j = i2 & 7, lane = (i2 >> 3) & 63, rest = i2 >> 9;
    int nt = rest % 8, ks = rest / 8;
    int k   = ks * 32 + ((lane >> 4) << 3) + j;        // freq bin
    int mel = nt * 16 + (lane & 15);
    float v = 0.f;
    if (k <= 200) {
      double mhi = 2595.0 * log10(1.0 + 8000.0 / 700.0);
      double ml = mhi * (double)mel / 129.0;
      double mc = mhi * (double)(mel + 1) / 129.0;
      double mr = mhi * (double)(mel + 2) / 129.0;
      double fl = 700.0 * (pow(10.0, ml / 2595.0) - 1.0);
      double fc = 700.0 * (pow(10.0, mc / 2595.0) - 1.0);
      double fr = 700.0 * (pow(10.0, mr / 2595.0) - 1.0);
      double f  = 40.0 * (double)k;
      double wv = fmin((f - fl) / (fc - fl), (fr - f) / (fr - fc));
      v = (float)fmax(0.0, wv);
    }
    ws[idx] = f2h(v);
  }
}

// ---- Kernel A: radix-2 DFT (E/O half-GEMMs, shared basis) -> combine -> mel ----
// 320 threads = 5 waves; DFT n-tiles {3,3,3,3,1}; acc_e+acc_o = 72 AGPRs.
template <int MT>
__global__ __launch_bounds__(320) __attribute__((amdgpu_waves_per_eu(3)))
void dft_mel_kernel(const float* __restrict__ audio, const unsigned short* __restrict__ ws,
                    unsigned short* __restrict__ outu)
{
  constexpr int AU = (MT == 3) ? 7968 : 2848;          // staged u16 (covers ks*64+lg*16+15)
  __shared__ unsigned short au[AU];
  __shared__ unsigned short pw16[MT * 16 * PW_STRIDE];
  __shared__ unsigned short winl[WIN_ELEMS];           // window frags, LDS broadcast
  const int tid = threadIdx.x;
  const int bid = blockIdx.x;
  const int r  = (MT == 3) ? (bid >> 2) : bid;
  const int t0 = (MT == 3) ? ((bid & 3) * 48) : 192;
  const float* __restrict__ ab = audio + (size_t)r * NS;
  const int g0 = t0 * 160 - PAD;

  // phase 1: stage audio fp16 (reflect pad) vectorized; win frags -> LDS; zero pw bins 201..224
  {
    constexpr int nchunk = AU / 8;
    for (int ci = tid; ci < nchunk; ci += 320) {
      half8 hv;
      int gbase = g0 + ci * 8;
      if (gbase >= 0 && gbase + 7 < NS) {
        const float4* p = (const float4*)(ab + gbase);
        float4 x0 = p[0], x1 = p[1];
        hv[0] = (_Float16)x0.x; hv[1] = (_Float16)x0.y;
        hv[2] = (_Float16)x0.z; hv[3] = (_Float16)x0.w;
        hv[4] = (_Float16)x1.x; hv[5] = (_Float16)x1.y;
        hv[6] = (_Float16)x1.z; hv[7] = (_Float16)x1.w;
      } else {
        #pragma unroll
        for (int j = 0; j < 8; ++j) {
          int g = gbase + j;
          if (g < 0) g = -g;
          if (g >= NS) g = 2 * NS - 2 - g;
          hv[j] = (_Float16)ab[g];
        }
      }
      *(half8*)(au + swz(ci * 8)) = hv;
    }
    for (int i = tid; i < WIN_ELEMS; i += 320) winl[i] = ws[BAS2_ELEMS + i];
    for (int i = tid; i < MT * 16 * 24; i += 320) {
      int row = i / 24, c = 201 + (i % 24);
      pw16[row * PW_STRIDE + c] = 0;
    }
  }
  __syncthreads();

  const int w = tid >> 6, lane = tid & 63, lr = lane & 15, lg = lane >> 4;
  const int ntc = (w == 4) ? 1 : 3;                    // DFT n-tiles this wave
  const int nt0 = w * 3;

  // phase 2: E/O half-GEMMs. Shared trig basis; window applied to A-fragments in fp16.
  f32x4 acc_e[MT][3], acc_o[MT][3];
  #pragma unroll
  for (int mm = 0; mm < MT; ++mm)
    #pragma unroll
    for (int n = 0; n < 3; ++n) {
      acc_e[mm][n] = (f32x4){0.f, 0.f, 0.f, 0.f};
      acc_o[mm][n] = (f32x4){0.f, 0.f, 0.f, 0.f};
    }
  for (int ks = 0; ks < 7; ++ks) {
    half8 Bf[3];
    #pragma unroll
    for (int n = 0; n < 3; ++n)
      if (n < ntc)
        Bf[n] = *(const half8*)(ws + ((size_t)((ks * NT2 + nt0 + n) * 64 + lane)) * 8);
    half8 We = *(const half8*)(winl + ((0 * 7 + ks) * 4 + lg) * 8);
    half8 Wo = *(const half8*)(winl + ((1 * 7 + ks) * 4 + lg) * 8);
    #pragma unroll
    for (int mm = 0; mm < MT; ++mm) {
      int base = mm * 2560 + lr * 160 + ks * 64 + lg * 16;
      half8 r0 = *(const half8*)(au + swz(base));
      half8 r1 = *(const half8*)(au + swz(base + 8));
      half8 ae, ao;
      #pragma unroll
      for (int j = 0; j < 4; ++j) {
        ae[j] = r0[2 * j];     ao[j] = r0[2 * j + 1];
        ae[j + 4] = r1[2 * j]; ao[j + 4] = r1[2 * j + 1];
      }
      ae = ae * We;                                    // window (fp16 packed mul)
      ao = ao * Wo;
      #pragma unroll
      for (int n = 0; n < 3; ++n)
        if (n < ntc) {
          acc_e[mm][n] = __builtin_amdgcn_mfma_f32_16x16x32_f16(ae, Bf[n], acc_e[mm][n], 0, 0, 0);
          acc_o[mm][n] = __builtin_amdgcn_mfma_f32_16x16x32_f16(ao, Bf[n], acc_o[mm][n], 0, 0, 0);
        }
    }
  }
  __syncthreads();   // audio reads done

  // phase 3: radix combine -> power. Lane pair (lr, lr^1) holds (cos, sin) cols of bin k'.
  // X[k'] = E + W^k' O ; X[200-k'] via conjugate symmetry. Even lane writes k', odd 200-k'.
  #pragma unroll
  for (int n = 0; n < 3; ++n)
    if (n < ntc) {
      int kp = (nt0 + n) * 8 + (lr >> 1);              // bin k' of this lane pair
      float th = (float)kp * 0.015707963267948967f;    // 2*pi*k'/400
      float cth = cosf(th), sth = sinf(th);
      bool odd = (lr & 1);
      #pragma unroll
      for (int mm = 0; mm < MT; ++mm) {
        #pragma unroll
        for (int j = 0; j < 4; ++j) {
          float ev = acc_e[mm][n][j], ov = acc_o[mm][n][j];
          float ep = dppswap(ev),     op = dppswap(ov);
          float ec = odd ? ep : ev,   es = odd ? ev : ep;
          float oc = odd ? op : ov,   os = odd ? ov : op;
          float u  = cth * oc - sth * os;
          float v2 = cth * os + sth * oc;
          float a  = odd ? (ec - u)  : (ec + u);
          float b  = odd ? (es - v2) : (es + v2);
          float p  = a * a + b * b;
          if (kp <= 100) {
            int bin = odd ? (200 - kp) : kp;
            int row = mm * 16 + lg * 4 + j;
            pw16[row * PW_STRIDE + bin] = f2h(p);
          }
        }
      }
    }
  __syncthreads();

  // phase 4: mel = power x fb (MFMA); fb n-tiles over 5 waves {2,2,2,1,1}
  {
    const int fcnt = (w < 3) ? 2 : 1;
    const int f0   = (w < 3) ? 2 * w : 6 + (w - 3);
    unsigned short* __restrict__ outrow = outu + (size_t)r * OUT_ROW_U16 + MEL_OFF_U16;
    #pragma unroll
    for (int ff = 0; ff < 2; ++ff)
      if (ff < fcnt) {
        int fbnt = f0 + ff;
        half8 Fb[7];
        #pragma unroll
        for (int ks = 0; ks < 7; ++ks)
          Fb[ks] = *(const half8*)(ws + FB_OFF + ((size_t)((ks * 8 + fbnt) * 64 + lane)) * 8);
        int gm = fbnt * 16 + lr;
        #pragma unroll
        for (int mt = 0; mt < MT; ++mt) {
          const unsigned short* psrc = pw16 + (mt * 16 + lr) * PW_STRIDE + lg * 8;
          f32x4 a2 = (f32x4){0.f, 0.f, 0.f, 0.f};
          #pragma unroll
          for (int ks = 0; ks < 7; ++ks)
            a2 = __builtin_amdgcn_mfma_f32_16x16x32_f16(*(const half8*)(psrc + ks * 32),
                                                        Fb[ks], a2, 0, 0, 0);
          #pragma unroll
          for (int j = 0; j < 4; ++j) {
            int t = t0 + mt * 16 + lg * 4 + j;
            if (MT == 3 || t < NT)
              outrow[t * NMEL + gm] = f2h(a2[j]);
          }
        }
      }
  }
}

// ---- Kernel B: per (row, mel-half): 16-chunk parallel PCEN scan + resize ----
__global__ __launch_bounds__(1024)
void pcen_resize_kernel(unsigned short* __restrict__ outu)
{
  __shared__ unsigned short mel[NT * 64];
  __shared__ float carry[16][64];
  __shared__ float minb[16][64];
  const int tid = threadIdx.x;
  const int bid = blockIdx.x;
  const int r = bid >> 1, h = bid & 1;
  const unsigned short* src = outu + (size_t)r * OUT_ROW_U16 + MEL_OFF_U16 + h * 64;
  for (int i = tid; i < NT * 8; i += 1024) {
    int t = i >> 3, cc = i & 7;
    *(u32x4*)(mel + t * 64 + cc * 8) = *(const u32x4*)(src + t * 128 + cc * 8);
  }
  __syncthreads();

  const int m = tid & 63, c = tid >> 6;                // 16 chunks: 6, 13 x 15
  const int t0  = (c == 0) ? 0 : (6 + 13 * (c - 1));
  const int len = (c == 0) ? 6 : 13;

  float M = 0.f;
  for (int t = t0; t < t0 + len; ++t) {
    float e = h2f(mel[t * 64 + m]);
    M = (t == 0) ? e : fmaf(0.96f, M, 0.04f * e);
  }
  carry[c][m] = M;
  __syncthreads();
  if (c == 0) {
    float a13 = exp2f(13.0f * log2f(0.96f));           // 0.96^13
    float acc = carry[0][m];
    minb[1][m] = acc;
    #pragma unroll
    for (int cc = 2; cc < 16; ++cc) {
      acc = fmaf(a13, acc, carry[cc - 1][m]);
      minb[cc][m] = acc;
    }
  }
  __syncthreads();

  float Min = (c == 0) ? 0.f : minb[c][m];
  float wf = 1.f, Mloc = 0.f;
  for (int t = t0; t < t0 + len; ++t) {
    float e = h2f(mel[t * 64 + m]);
    Mloc = (t == 0) ? e : fmaf(0.96f, Mloc, 0.04f * e);
    wf *= 0.96f;
    float Mt = fmaf(wf, Min, Mloc);
    float dn = exp2f(0.8f * log2f(1e-8f + Mt));        // (1e-8+M)^0.8
    float pc = sqrtf(e / dn + 2.0f) - 1.41421356237309515f;
    mel[t * 64 + m] = f2h(pc);
  }
  __syncthreads();

  float* __restrict__ ob = (float*)outu + (size_t)r * TOUT * NMEL + h * 64;
  const float INVS = 201.0f / 192.0f;
  for (int i = c; i < TOUT; i += 16) {
    float ct = ((float)i + 0.5f) * INVS - 0.5f;
    int jlo = (int)ceilf(ct - INVS);
    int jhi = (int)floorf(ct + INVS);
    if (jlo < 0) jlo = 0;
    if (jhi > NT - 1) jhi = NT - 1;
    float wsum = 0.f, val = 0.f;
    for (int j = jlo; j <= jhi; ++j) {
      float wv = 1.0f - fabsf((float)j - ct) / INVS;
      if (wv > 0.f) { wsum += wv; val = fmaf(wv, h2f(mel[j * 64 + m]), val); }
    }
    ob[(size_t)i * NMEL + m] = val / wsum;
  }
}

extern "C" void kernel_launch(void* const* d_in, const int* in_sizes, int n_in,
                              void* d_out, int out_size, void* d_ws, size_t ws_size,
                              hipStream_t stream) {
  (void)in_sizes; (void)n_in; (void)out_size; (void)ws_size;
  unsigned short* ws = (unsigned short*)d_ws;
  const int total = FB_OFF + FB_ELEMS;
  setup_tables<<<(total + 255) / 256, 256, 0, stream>>>(ws);
  dft_mel_kernel<3><<<2048 * 4, 320, 0, stream>>>((const float*)d_in[0], ws,
                                                  (unsigned short*)d_out);
  dft_mel_kernel<1><<<2048, 320, 0, stream>>>((const float*)d_in[0], ws,
                                              (unsigned short*)d_out);
  pcen_resize_kernel<<<4096, 1024, 0, stream>>>((unsigned short*)d_out);
}

// Round 16
// 488.577 us; speedup vs baseline: 1.0586x; 1.0586x over previous
//
#include <hip/hip_runtime.h>
#include <math.h>

typedef __attribute__((ext_vector_type(8))) _Float16 half8;
typedef __attribute__((ext_vector_type(4))) float f32x4;
typedef __attribute__((ext_vector_type(4))) unsigned int u32x4;

namespace {
constexpr int NS = 32000, PAD = 200, NT = 201, TOUT = 192, NMEL = 128;
constexpr int PW_STRIDE = 236;                 // u16; 472B row stride
constexpr int NT2 = 13;                        // radix basis: N=208 (202 live), K=224 (200 live)
constexpr int BAS2_ELEMS = 7 * NT2 * 64 * 8;   // 46592 u16
constexpr int WIN_ELEMS  = 448;                // win frags [par][ks][lg][j], m = 2*(ks*32+lg*8+j)+par
constexpr int FB_OFF     = BAS2_ELEMS + WIN_ELEMS;   // 47040
constexpr int FB_ELEMS   = 7 * 8 * 64 * 8;     // 28672
constexpr int OUT_ROW_U16 = TOUT * NMEL * 2;   // 49152 u16 per out row
constexpr int MEL_OFF_U16 = OUT_ROW_U16 - NT * NMEL;  // mel fp16 packed in row tail
}

// swizzle for stride-80(u16) frame rows in E/O planes: XOR bit4 with bit6.
// Preserves 8-elem (b128) contiguity; splits 4-way bank groups to <=2-way.
__device__ __forceinline__ int swz2(int e) { return e ^ (((e >> 6) & 1) << 4); }
__device__ __forceinline__ unsigned short f2h(float f) {
  _Float16 h = (_Float16)f; return __builtin_bit_cast(unsigned short, h);
}
__device__ __forceinline__ float h2f(unsigned short u) {
  return (float)__builtin_bit_cast(_Float16, u);
}
__device__ __forceinline__ float dppswap(float v) {   // lane^1 within quads
  int iv = __builtin_bit_cast(int, v);
  return __builtin_bit_cast(float,
      __builtin_amdgcn_mov_dpp(iv, 0xB1, 0xF, 0xF, true));  // quad_perm [1,0,3,2]
}

// ws tables, fp16 (basis/fb verbatim R15; win frag re-indexed for plane reads):
//  [0, BAS2): radix DFT basis frag[ks][nt][lane][j]: n=ks*32+(lane>>4)*8+j, col=nt*16+(lane&15)
//             col even -> cos(2*pi*bin*n/200), odd -> sin; bin=col/2; zero n>=200 or col>=202
//  [BAS2, +448): window frags [par][ks][lg][j] = win[2*(ks*32+lg*8+j)+par] (0 for idx>=400)
//  [FB_OFF, +FB): mel fb frag[ks][nt][lane][j]
__global__ void setup_tables(unsigned short* __restrict__ ws) {
  int idx = blockIdx.x * 256 + threadIdx.x;
  if (idx < BAS2_ELEMS) {
    int j = idx & 7, lane = (idx >> 3) & 63, rest = idx >> 9;
    int nt = rest % NT2, ks = rest / NT2;
    int n   = ks * 32 + ((lane >> 4) << 3) + j;
    int col = nt * 16 + (lane & 15);
    float v = 0.f;
    if (n < 200 && col < 202) {
      int bin = col >> 1;
      int mm  = (bin * n) % 200;
      float th = (float)mm * 0.03141592653589793f;     // 2*pi/200
      v = (col & 1) ? sinf(th) : cosf(th);
    }
    ws[idx] = f2h(v);
  } else if (idx < FB_OFF) {
    int i2 = idx - BAS2_ELEMS;                          // [par][ks][lg][j]
    int j = i2 & 7, lg = (i2 >> 3) & 3, t = i2 >> 5;
    int ks = t % 7, par = t / 7;
    int m = 2 * (ks * 32 + lg * 8 + j) + par;
    float v = 0.f;
    if (m < 400) v = 0.5f * (1.0f - cosf((float)m * 0.015707963267948967f));
    ws[idx] = f2h(v);
  } else if (idx < FB_OFF + FB_ELEMS) {
    int i2 = idx - FB_OFF;
    int j = i2 & 7, lane = (i2 >> 3) & 63, rest = i2 >> 9;
    int nt = rest % 8, ks = rest / 8;
    int k   = ks * 32 + ((lane >> 4) << 3) + j;        // freq bin
    int mel = nt * 16 + (lane & 15);
    float v = 0.f;
    if (k <= 200) {
      double mhi = 2595.0 * log10(1.0 + 8000.0 / 700.0);
      double ml = mhi * (double)mel / 129.0;
      double mc = mhi * (double)(mel + 1) / 129.0;
      double mr = mhi * (double)(mel + 2) / 129.0;
      double fl = 700.0 * (pow(10.0, ml / 2595.0) - 1.0);
      double fc = 700.0 * (pow(10.0, mc / 2595.0) - 1.0);
      double fr = 700.0 * (pow(10.0, mr / 2595.0) - 1.0);
      double f  = 40.0 * (double)k;
      double wv = fmin((f - fl) / (fc - fl), (fr - f) / (fr - fc));
      v = (float)fmax(0.0, wv);
    }
    ws[idx] = f2h(v);
  }
}

// ---- Kernel A: radix-2 DFT with PRE-DEINTERLEAVED E/O planes (zero shuffle VALU) ----
// 320 threads = 5 waves; DFT n-tiles {3,3,3,3,1}; frame t even samples at au_e + t*80.
template <int MT>
__global__ __launch_bounds__(320) __attribute__((amdgpu_waves_per_eu(3)))
void dft_mel_kernel(const float* __restrict__ audio, const unsigned short* __restrict__ ws,
                    unsigned short* __restrict__ outu)
{
  constexpr int AUE = (MT == 3) ? 4096 : 1536;         // u16 per plane (need 3984 / 1432)
  __shared__ unsigned short au_e[AUE];
  __shared__ unsigned short au_o[AUE];
  __shared__ unsigned short pw16[MT * 16 * PW_STRIDE];
  __shared__ unsigned short winl[WIN_ELEMS];
  const int tid = threadIdx.x;
  const int bid = blockIdx.x;
  const int r  = (MT == 3) ? (bid >> 2) : bid;
  const int t0 = (MT == 3) ? ((bid & 3) * 48) : 192;
  const float* __restrict__ ab = audio + (size_t)r * NS;
  const int g0 = t0 * 160 - PAD;                       // even; g0 % 4 == 0 (float4-safe)

  // phase 1: stage E/O planes fp16 (reflect pad): 4x float4 -> 2x half8 -> 2x b128
  {
    constexpr int nchunk = AUE / 8;
    for (int ci = tid; ci < nchunk; ci += 320) {
      half8 he, ho;
      int gbase = g0 + ci * 16;
      if (gbase >= 0 && gbase + 15 < NS) {
        const float4* p = (const float4*)(ab + gbase);
        float4 x0 = p[0], x1 = p[1], x2 = p[2], x3 = p[3];
        he[0]=(_Float16)x0.x; ho[0]=(_Float16)x0.y; he[1]=(_Float16)x0.z; ho[1]=(_Float16)x0.w;
        he[2]=(_Float16)x1.x; ho[2]=(_Float16)x1.y; he[3]=(_Float16)x1.z; ho[3]=(_Float16)x1.w;
        he[4]=(_Float16)x2.x; ho[4]=(_Float16)x2.y; he[5]=(_Float16)x2.z; ho[5]=(_Float16)x2.w;
        he[6]=(_Float16)x3.x; ho[6]=(_Float16)x3.y; he[7]=(_Float16)x3.z; ho[7]=(_Float16)x3.w;
      } else {
        #pragma unroll
        for (int j = 0; j < 8; ++j) {
          int g = gbase + 2 * j;
          int ge = (g < 0) ? -g : ((g >= NS) ? 2 * NS - 2 - g : g);
          int g2 = g + 1;
          int go = (g2 < 0) ? -g2 : ((g2 >= NS) ? 2 * NS - 2 - g2 : g2);
          he[j] = (_Float16)ab[ge];
          ho[j] = (_Float16)ab[go];
        }
      }
      *(half8*)(au_e + swz2(ci * 8)) = he;
      *(half8*)(au_o + swz2(ci * 8)) = ho;
    }
    for (int i = tid; i < WIN_ELEMS; i += 320) winl[i] = ws[BAS2_ELEMS + i];
    for (int i = tid; i < MT * 16 * 24; i += 320) {
      int row = i / 24, c = 201 + (i % 24);
      pw16[row * PW_STRIDE + c] = 0;
    }
  }
  __syncthreads();

  const int w = tid >> 6, lane = tid & 63, lr = lane & 15, lg = lane >> 4;
  const int ntc = (w == 4) ? 1 : 3;                    // DFT n-tiles this wave
  const int nt0 = w * 3;

  // phase 2: E/O half-GEMMs; A-fragments are direct b128 plane reads * window
  f32x4 acc_e[MT][3], acc_o[MT][3];
  #pragma unroll
  for (int mm = 0; mm < MT; ++mm)
    #pragma unroll
    for (int n = 0; n < 3; ++n) {
      acc_e[mm][n] = (f32x4){0.f, 0.f, 0.f, 0.f};
      acc_o[mm][n] = (f32x4){0.f, 0.f, 0.f, 0.f};
    }
  for (int ks = 0; ks < 7; ++ks) {
    half8 Bf[3];
    #pragma unroll
    for (int n = 0; n < 3; ++n)
      if (n < ntc)
        Bf[n] = *(const half8*)(ws + ((size_t)((ks * NT2 + nt0 + n) * 64 + lane)) * 8);
    half8 We = *(const half8*)(winl + ((0 * 7 + ks) * 4 + lg) * 8);
    half8 Wo = *(const half8*)(winl + ((1 * 7 + ks) * 4 + lg) * 8);
    #pragma unroll
    for (int mm = 0; mm < MT; ++mm) {
      int base = (mm * 16 + lr) * 80 + ks * 32 + lg * 8;
      half8 ae = *(const half8*)(au_e + swz2(base)) * We;
      half8 ao = *(const half8*)(au_o + swz2(base)) * Wo;
      #pragma unroll
      for (int n = 0; n < 3; ++n)
        if (n < ntc) {
          acc_e[mm][n] = __builtin_amdgcn_mfma_f32_16x16x32_f16(ae, Bf[n], acc_e[mm][n], 0, 0, 0);
          acc_o[mm][n] = __builtin_amdgcn_mfma_f32_16x16x32_f16(ao, Bf[n], acc_o[mm][n], 0, 0, 0);
        }
    }
  }
  __syncthreads();

  // phase 3: radix combine -> power (verbatim R15). Lane pair (lr,lr^1) = (cos,sin) of bin k'.
  // X[k'] = E + W^k' O ; X[200-k'] by conjugate symmetry. Even lane writes k', odd 200-k'.
  #pragma unroll
  for (int n = 0; n < 3; ++n)
    if (n < ntc) {
      int kp = (nt0 + n) * 8 + (lr >> 1);
      float th = (float)kp * 0.015707963267948967f;    // 2*pi*k'/400
      float cth = cosf(th), sth = sinf(th);
      bool odd = (lr & 1);
      #pragma unroll
      for (int mm = 0; mm < MT; ++mm) {
        #pragma unroll
        for (int j = 0; j < 4; ++j) {
          float ev = acc_e[mm][n][j], ov = acc_o[mm][n][j];
          float ep = dppswap(ev),     op = dppswap(ov);
          float ec = odd ? ep : ev,   es = odd ? ev : ep;
          float oc = odd ? op : ov,   os = odd ? ov : op;
          float u  = cth * oc - sth * os;
          float v2 = cth * os + sth * oc;
          float a  = odd ? (ec - u)  : (ec + u);
          float b  = odd ? (es - v2) : (es + v2);
          float p  = a * a + b * b;
          if (kp <= 100) {
            int bin = odd ? (200 - kp) : kp;
            int row = mm * 16 + lg * 4 + j;
            pw16[row * PW_STRIDE + bin] = f2h(p);
          }
        }
      }
    }
  __syncthreads();

  // phase 4: mel = power x fb (MFMA); fb n-tiles over 5 waves {2,2,2,1,1} (verbatim R15)
  {
    const int fcnt = (w < 3) ? 2 : 1;
    const int f0   = (w < 3) ? 2 * w : 6 + (w - 3);
    unsigned short* __restrict__ outrow = outu + (size_t)r * OUT_ROW_U16 + MEL_OFF_U16;
    #pragma unroll
    for (int ff = 0; ff < 2; ++ff)
      if (ff < fcnt) {
        int fbnt = f0 + ff;
        half8 Fb[7];
        #pragma unroll
        for (int ks = 0; ks < 7; ++ks)
          Fb[ks] = *(const half8*)(ws + FB_OFF + ((size_t)((ks * 8 + fbnt) * 64 + lane)) * 8);
        int gm = fbnt * 16 + lr;
        #pragma unroll
        for (int mt = 0; mt < MT; ++mt) {
          const unsigned short* psrc = pw16 + (mt * 16 + lr) * PW_STRIDE + lg * 8;
          f32x4 a2 = (f32x4){0.f, 0.f, 0.f, 0.f};
          #pragma unroll
          for (int ks = 0; ks < 7; ++ks)
            a2 = __builtin_amdgcn_mfma_f32_16x16x32_f16(*(const half8*)(psrc + ks * 32),
                                                        Fb[ks], a2, 0, 0, 0);
          #pragma unroll
          for (int j = 0; j < 4; ++j) {
            int t = t0 + mt * 16 + lg * 4 + j;
            if (MT == 3 || t < NT)
              outrow[t * NMEL + gm] = f2h(a2[j]);
          }
        }
      }
  }
}

// ---- Kernel B: per (row, mel-half): 16-chunk parallel PCEN scan + resize (verbatim) ----
__global__ __launch_bounds__(1024)
void pcen_resize_kernel(unsigned short* __restrict__ outu)
{
  __shared__ unsigned short mel[NT * 64];
  __shared__ float carry[16][64];
  __shared__ float minb[16][64];
  const int tid = threadIdx.x;
  const int bid = blockIdx.x;
  const int r = bid >> 1, h = bid & 1;
  const unsigned short* src = outu + (size_t)r * OUT_ROW_U16 + MEL_OFF_U16 + h * 64;
  for (int i = tid; i < NT * 8; i += 1024) {
    int t = i >> 3, cc = i & 7;
    *(u32x4*)(mel + t * 64 + cc * 8) = *(const u32x4*)(src + t * 128 + cc * 8);
  }
  __syncthreads();

  const int m = tid & 63, c = tid >> 6;                // 16 chunks: 6, 13 x 15
  const int t0  = (c == 0) ? 0 : (6 + 13 * (c - 1));
  const int len = (c == 0) ? 6 : 13;

  float M = 0.f;
  for (int t = t0; t < t0 + len; ++t) {
    float e = h2f(mel[t * 64 + m]);
    M = (t == 0) ? e : fmaf(0.96f, M, 0.04f * e);
  }
  carry[c][m] = M;
  __syncthreads();
  if (c == 0) {
    float a13 = exp2f(13.0f * log2f(0.96f));           // 0.96^13
    float acc = carry[0][m];
    minb[1][m] = acc;
    #pragma unroll
    for (int cc = 2; cc < 16; ++cc) {
      acc = fmaf(a13, acc, carry[cc - 1][m]);
      minb[cc][m] = acc;
    }
  }
  __syncthreads();

  float Min = (c == 0) ? 0.f : minb[c][m];
  float wf = 1.f, Mloc = 0.f;
  for (int t = t0; t < t0 + len; ++t) {
    float e = h2f(mel[t * 64 + m]);
    Mloc = (t == 0) ? e : fmaf(0.96f, Mloc, 0.04f * e);
    wf *= 0.96f;
    float Mt = fmaf(wf, Min, Mloc);
    float dn = exp2f(0.8f * log2f(1e-8f + Mt));        // (1e-8+M)^0.8
    float pc = sqrtf(e / dn + 2.0f) - 1.41421356237309515f;
    mel[t * 64 + m] = f2h(pc);
  }
  __syncthreads();

  float* __restrict__ ob = (float*)outu + (size_t)r * TOUT * NMEL + h * 64;
  const float INVS = 201.0f / 192.0f;
  for (int i = c; i < TOUT; i += 16) {
    float ct = ((float)i + 0.5f) * INVS - 0.5f;
    int jlo = (int)ceilf(ct - INVS);
    int jhi = (int)floorf(ct + INVS);
    if (jlo < 0) jlo = 0;
    if (jhi > NT - 1) jhi = NT - 1;
    float wsum = 0.f, val = 0.f;
    for (int j = jlo; j <= jhi; ++j) {
      float wv = 1.0f - fabsf((float)j - ct) / INVS;
      if (wv > 0.f) { wsum += wv; val = fmaf(wv, h2f(mel[j * 64 + m]), val); }
    }
    ob[(size_t)i * NMEL + m] = val / wsum;
  }
}

extern "C" void kernel_launch(void* const* d_in, const int* in_sizes, int n_in,
                              void* d_out, int out_size, void* d_ws, size_t ws_size,
                              hipStream_t stream) {
  (void)in_sizes; (void)n_in; (void)out_size; (void)ws_size;
  unsigned short* ws = (unsigned short*)d_ws;
  const int total = FB_OFF + FB_ELEMS;
  setup_tables<<<(total + 255) / 256, 256, 0, stream>>>(ws);
  dft_mel_kernel<3><<<2048 * 4, 320, 0, stream>>>((const float*)d_in[0], ws,
                                                  (unsigned short*)d_out);
  dft_mel_kernel<1><<<2048, 320, 0, stream>>>((const float*)d_in[0], ws,
                                              (unsigned short*)d_out);
  pcen_resize_kernel<<<4096, 1024, 0, stream>>>((unsigned short*)d_out);
}